// Round 7
// baseline (154.026 us; speedup 1.0000x reference)
//
#include <hip/hip_runtime.h>
#include <math.h>

#define NT     128
#define NB     16
#define NH     512
#define SEQ_L  1024
#define FFT_N  2048
#define RS     0.70710678118654752f
#define C16    0.92387953251128675f   // cos(pi/8)
#define S16    0.38268343236508977f   // sin(pi/8)

// SoA LDS, pad every 16 floats: <=2-way bank aliasing on all access patterns.
#define P(x) ((x) + ((x) >> 4))
#define BUF_SZ 2176   // P(2047) = 2174

__device__ __forceinline__ float2 cmul(float2 a, float2 b) {
    return make_float2(a.x * b.x - a.y * b.y, a.x * b.y + a.y * b.x);
}
__device__ __forceinline__ float2 cmulj(float2 a, float2 b) {  // a * conj(b)
    return make_float2(a.x * b.x + a.y * b.y, a.y * b.x - a.x * b.y);
}
__device__ __forceinline__ float2 cadd(float2 a, float2 b) { return make_float2(a.x + b.x, a.y + b.y); }
__device__ __forceinline__ float2 csub(float2 a, float2 b) { return make_float2(a.x - b.x, a.y - b.y); }

// In-place DFT4, natural order. SIGN=-1 fwd, SIGN=+1 inverse.
template <int SIGN>
__device__ __forceinline__ void dft4(float2 x[4]) {
    float2 s0 = cadd(x[0], x[2]), s1 = csub(x[0], x[2]);
    float2 s2 = cadd(x[1], x[3]), s3 = csub(x[1], x[3]);
    x[0] = cadd(s0, s2);
    x[2] = csub(s0, s2);
    if (SIGN < 0) {
        x[1] = make_float2(s1.x + s3.y, s1.y - s3.x);  // s1 - i*s3
        x[3] = make_float2(s1.x - s3.y, s1.y + s3.x);  // s1 + i*s3
    } else {
        x[1] = make_float2(s1.x - s3.y, s1.y + s3.x);
        x[3] = make_float2(s1.x + s3.y, s1.y - s3.x);
    }
}

// In-place DFT8, natural order (verified R4-R6).
template <int SIGN>
__device__ __forceinline__ void dft8(float2 x[8]) {
    float2 e0 = cadd(x[0], x[4]), e1 = cadd(x[1], x[5]);
    float2 e2 = cadd(x[2], x[6]), e3 = cadd(x[3], x[7]);
    float2 o0 = csub(x[0], x[4]), o1 = csub(x[1], x[5]);
    float2 o2 = csub(x[2], x[6]), o3 = csub(x[3], x[7]);
    float2 t1, t2, t3;
    if (SIGN < 0) {
        t1 = make_float2(RS * (o1.x + o1.y), RS * (o1.y - o1.x));
        t2 = make_float2(o2.y, -o2.x);
        t3 = make_float2(-RS * (o3.x - o3.y), -RS * (o3.x + o3.y));
    } else {
        t1 = make_float2(RS * (o1.x - o1.y), RS * (o1.x + o1.y));
        t2 = make_float2(-o2.y, o2.x);
        t3 = make_float2(RS * (-o3.x - o3.y), RS * (o3.x - o3.y));
    }
    float2 s0 = cadd(e0, e2), s1 = csub(e0, e2), s2 = cadd(e1, e3), s3 = csub(e1, e3);
    x[0] = cadd(s0, s2);
    x[4] = csub(s0, s2);
    float2 u0 = cadd(o0, t2), u1 = csub(o0, t2), u2 = cadd(t1, t3), u3 = csub(t1, t3);
    x[1] = cadd(u0, u2);
    x[5] = csub(u0, u2);
    if (SIGN < 0) {
        x[2] = make_float2(s1.x + s3.y, s1.y - s3.x);
        x[6] = make_float2(s1.x - s3.y, s1.y + s3.x);
        x[3] = make_float2(u1.x + u3.y, u1.y - u3.x);
        x[7] = make_float2(u1.x - u3.y, u1.y + u3.x);
    } else {
        x[2] = make_float2(s1.x - s3.y, s1.y + s3.x);
        x[6] = make_float2(s1.x + s3.y, s1.y - s3.x);
        x[3] = make_float2(u1.x - u3.y, u1.y + u3.x);
        x[7] = make_float2(u1.x + u3.y, u1.y - u3.x);
    }
}

// Internal W16 twiddles for the 4x4 CT decomposition of DFT16.
template <int SIGN>
__device__ __forceinline__ void dft16_twiddle(float2 v[4][4]) {
    const float sg = (SIGN < 0) ? -1.f : 1.f;
    const float2 W1 = make_float2(C16, sg * S16);
    const float2 W2 = make_float2(RS, sg * RS);
    const float2 W3 = make_float2(S16, sg * C16);
    const float2 W6 = make_float2(-RS, sg * RS);
    const float2 W9 = make_float2(-C16, -sg * S16);
    v[1][1] = cmul(v[1][1], W1);
    v[1][2] = cmul(v[1][2], W2);
    v[1][3] = cmul(v[1][3], W3);
    v[2][1] = cmul(v[2][1], W2);
    v[2][2] = make_float2(-sg * v[2][2].y, sg * v[2][2].x);  // *W16^4
    v[2][3] = cmul(v[2][3], W6);
    v[3][1] = cmul(v[3][1], W3);
    v[3][2] = cmul(v[3][2], W6);
    v[3][3] = cmul(v[3][3], W9);
}

// Full in-place DFT16, natural order.
template <int SIGN>
__device__ __forceinline__ void dft16(float2 x[16]) {
    float2 v[4][4];
#pragma unroll
    for (int n0 = 0; n0 < 4; ++n0) {
        float2 a[4] = {x[n0], x[n0 + 4], x[n0 + 8], x[n0 + 12]};
        dft4<SIGN>(a);
        v[n0][0] = a[0]; v[n0][1] = a[1]; v[n0][2] = a[2]; v[n0][3] = a[3];
    }
    dft16_twiddle<SIGN>(v);
#pragma unroll
    for (int k0 = 0; k0 < 4; ++k0) {
        float2 a[4] = {v[0][k0], v[1][k0], v[2][k0], v[3][k0]};
        dft4<SIGN>(a);
        x[k0] = a[0]; x[k0 + 4] = a[1]; x[k0 + 8] = a[2]; x[k0 + 12] = a[3];
    }
}

// Forward DFT16 with inputs 8..15 implicitly zero.
__device__ __forceinline__ void dft16_zero8(const float2 z[8], float2 x[16]) {
    float2 v[4][4];
#pragma unroll
    for (int n0 = 0; n0 < 4; ++n0) {
        float2 a = z[n0], b = z[n0 + 4];
        v[n0][0] = cadd(a, b);
        v[n0][1] = make_float2(a.x + b.y, a.y - b.x);   // a - i*b
        v[n0][2] = csub(a, b);
        v[n0][3] = make_float2(a.x - b.y, a.y + b.x);   // a + i*b
    }
    dft16_twiddle<-1>(v);
#pragma unroll
    for (int k0 = 0; k0 < 4; ++k0) {
        float2 a[4] = {v[0][k0], v[1][k0], v[2][k0], v[3][k0]};
        dft4<-1>(a);
        x[k0] = a[0]; x[k0 + 4] = a[1]; x[k0 + 8] = a[2]; x[k0 + 12] = a[3];
    }
}

// Inverse DFT16 computing only outputs 0..7.
__device__ __forceinline__ void dft16_inv_low8(const float2 x[16], float2 y[8]) {
    float2 v[4][4];
#pragma unroll
    for (int n0 = 0; n0 < 4; ++n0) {
        float2 a[4] = {x[n0], x[n0 + 4], x[n0 + 8], x[n0 + 12]};
        dft4<+1>(a);
        v[n0][0] = a[0]; v[n0][1] = a[1]; v[n0][2] = a[2]; v[n0][3] = a[3];
    }
    dft16_twiddle<+1>(v);
#pragma unroll
    for (int k0 = 0; k0 < 4; ++k0) {
        float2 x0 = v[0][k0], x1 = v[1][k0], x2 = v[2][k0], x3 = v[3][k0];
        float2 s0 = cadd(x0, x2), s1 = csub(x0, x2);
        float2 s2 = cadd(x1, x3), s3 = csub(x1, x3);
        y[k0]     = cadd(s0, s2);                             // k1 = 0
        y[k0 + 4] = make_float2(s1.x - s3.y, s1.y + s3.x);    // k1 = 1
    }
}

// Apply x[c] *= a^c (CONJ=0) or x[c] *= conj(a^c) (CONJ=1), c = 1..15.
// Log-depth power products (depth <=5 vs 15 for a serial chain).
template <int CONJ>
__device__ __forceinline__ void tw_apply16(float2 x[16], float2 a) {
#define AP(v, w) (v) = CONJ ? cmulj((v), (w)) : cmul((v), (w))
    AP(x[1], a);
    float2 w2 = cmul(a, a);      AP(x[2], w2);
    float2 w3 = cmul(w2, a);     AP(x[3], w3);
    float2 w4 = cmul(w2, w2);    AP(x[4], w4);
    float2 w5 = cmul(w4, a);     AP(x[5], w5);
    float2 w6 = cmul(w4, w2);    AP(x[6], w6);
    float2 w7 = cmul(w6, a);     AP(x[7], w7);
    float2 w8 = cmul(w4, w4);    AP(x[8], w8);
    float2 w9 = cmul(w8, a);     AP(x[9], w9);
    float2 w10 = cmul(w8, w2);   AP(x[10], w10);
    float2 w11 = cmul(w10, a);   AP(x[11], w11);
    float2 w12 = cmul(w8, w4);   AP(x[12], w12);
    float2 w13 = cmul(w12, a);   AP(x[13], w13);
    float2 w14 = cmul(w12, w2);  AP(x[14], w14);
    float2 w15 = cmul(w14, a);   AP(x[15], w15);
#undef AP
}

// ---- Single fused kernel: 3 blocks per h; each computes k_f[h] into
// registers (kreg), then processes 2-3 pair-tiles (two u rows each). ----
__global__ __launch_bounds__(NT, 3) void mono_kernel(const float* __restrict__ u,
                                                     const float* __restrict__ kin,
                                                     const float* __restrict__ D,
                                                     float* __restrict__ out) {
    __shared__ float re[BUF_SZ];
    __shared__ float im[BUF_SZ];
    __shared__ float2 twlds[NT];
    const int t = threadIdx.x;
    const int h = blockIdx.x & (NH - 1);
    const int j3 = blockIdx.x >> 9;   // 0..2: which subset of batch-pairs
    float2 w1;
    {
        float sv, cv;
        sincosf(-6.283185307179586f * (float)t / (float)FFT_N, &sv, &cv);
        w1 = make_float2(cv, sv);
        twlds[t] = w1;
    }
    const int cblk = t >> 3, r = t & 7;
    const int base = 128 * cblk + r;

    // ---- k_f[h] -> registers (s1, s2 through LDS; final dft8 in regs) ----
    float2 kreg[2][8];
    {
        const float* krow = kin + (size_t)h * SEQ_L;
        float2 z[8], x[16];
#pragma unroll
        for (int m = 0; m < 8; ++m) z[m] = make_float2(krow[t + 128 * m], 0.f);
        dft16_zero8(z, x);
        tw_apply16<0>(x, w1);
#pragma unroll
        for (int c = 0; c < 16; ++c) {
            const int id = P(t + 128 * c);
            re[id] = x[c].x; im[id] = x[c].y;
        }
        __syncthreads();   // publishes twlds + k-s1
        const float2 wsk = twlds[16 * r];
#pragma unroll
        for (int c = 0; c < 16; ++c) {
            const int id = P(base + 8 * c);
            x[c] = make_float2(re[id], im[id]);
        }
        dft16<-1>(x);
        tw_apply16<0>(x, wsk);
#pragma unroll
        for (int c = 0; c < 16; ++c) {
            const int id = P(base + 8 * c);
            re[id] = x[c].x; im[id] = x[c].y;
        }
        __syncthreads();
#pragma unroll
        for (int gi = 0; gi < 2; ++gi) {
            const int g = 2 * t + gi;
            float2 xk[8];
#pragma unroll
            for (int l = 0; l < 8; ++l) {
                const int id = P(8 * g + l);
                xk[l] = make_float2(re[id], im[id]);
            }
            dft8<-1>(xk);
#pragma unroll
            for (int l = 0; l < 8; ++l) kreg[gi][l] = xk[l];
        }
        __syncthreads();   // LDS free for tile reuse
    }

    const float2 ws = twlds[16 * r];   // W_128^r
    const float Dh = D[h];
    const float invN = 1.0f / (float)FFT_N;

    for (int bp = j3; bp < 8; bp += 3) {
        if (bp != j3) __syncthreads();   // protect LDS from previous tile reads
        const size_t row0 = (size_t)(2 * bp) * NH + h;
        const size_t row1 = row0 + NH;
        const float* u0 = u + row0 * SEQ_L;
        const float* u1 = u + row1 * SEQ_L;
        // s1 fwd (write-only)
        {
            float2 z[8], x[16];
#pragma unroll
            for (int m = 0; m < 8; ++m)
                z[m] = make_float2(u0[t + 128 * m], u1[t + 128 * m]);
            dft16_zero8(z, x);
            tw_apply16<0>(x, w1);
#pragma unroll
            for (int c = 0; c < 16; ++c) {
                const int id = P(t + 128 * c);
                re[id] = x[c].x; im[id] = x[c].y;
            }
        }
        __syncthreads();
        // s2 fwd (in-place)
        {
            float2 x[16];
#pragma unroll
            for (int c = 0; c < 16; ++c) {
                const int id = P(base + 8 * c);
                x[c] = make_float2(re[id], im[id]);
            }
            dft16<-1>(x);
            tw_apply16<0>(x, ws);
#pragma unroll
            for (int c = 0; c < 16; ++c) {
                const int id = P(base + 8 * c);
                re[id] = x[c].x; im[id] = x[c].y;
            }
        }
        __syncthreads();
        // mid: dft8 fwd + *kreg + dft8 inv (registers only)
        {
#pragma unroll
            for (int gi = 0; gi < 2; ++gi) {
                const int g = 2 * t + gi;
                float2 x[8];
#pragma unroll
                for (int l = 0; l < 8; ++l) {
                    const int id = P(8 * g + l);
                    x[l] = make_float2(re[id], im[id]);
                }
                dft8<-1>(x);
#pragma unroll
                for (int l = 0; l < 8; ++l) x[l] = cmul(x[l], kreg[gi][l]);
                dft8<+1>(x);
#pragma unroll
                for (int l = 0; l < 8; ++l) {
                    const int id = P(8 * g + l);
                    re[id] = x[l].x; im[id] = x[l].y;
                }
            }
        }
        __syncthreads();
        // inv s2 (adjoint: conj twiddle then inverse butterfly; in-place)
        {
            float2 x[16];
#pragma unroll
            for (int c = 0; c < 16; ++c) {
                const int id = P(base + 8 * c);
                x[c] = make_float2(re[id], im[id]);
            }
            tw_apply16<1>(x, ws);
            dft16<+1>(x);
#pragma unroll
            for (int c = 0; c < 16; ++c) {
                const int id = P(base + 8 * c);
                re[id] = x[c].x; im[id] = x[c].y;
            }
        }
        __syncthreads();
        // inv s1 + epilogue (low 8 outputs only); u re-loaded (L2/L3 hot)
        {
            float2 x[16];
#pragma unroll
            for (int c = 0; c < 16; ++c) {
                const int id = P(t + 128 * c);
                x[c] = make_float2(re[id], im[id]);
            }
            tw_apply16<1>(x, w1);
            float2 y[8];
            dft16_inv_low8(x, y);
            float* o0row = out + row0 * SEQ_L;
            float* o1row = out + row1 * SEQ_L;
#pragma unroll
            for (int m = 0; m < 8; ++m) {
                o0row[t + 128 * m] = y[m].x * invN + u0[t + 128 * m] * Dh;
                o1row[t + 128 * m] = y[m].y * invN + u1[t + 128 * m] * Dh;
            }
        }
    }
}

extern "C" void kernel_launch(void* const* d_in, const int* in_sizes, int n_in,
                              void* d_out, int out_size, void* d_ws, size_t ws_size,
                              hipStream_t stream) {
    const float* u = (const float*)d_in[0];
    const float* k = (const float*)d_in[1];
    const float* D = (const float*)d_in[2];
    float* out = (float*)d_out;

    mono_kernel<<<3 * NH, NT, 0, stream>>>(u, k, D, out);
}

// Round 8
// 113.414 us; speedup vs baseline: 1.3581x; 1.3581x over previous
//
#include <hip/hip_runtime.h>
#include <math.h>

#define NT     128
#define NB     16
#define NH     512
#define SEQ_L  1024
#define FFT_N  2048
#define RS     0.70710678118654752f
#define C16    0.92387953251128675f   // cos(pi/8)
#define S16    0.38268343236508977f   // sin(pi/8)

// SoA LDS, pad every 16 floats: <=2-way bank aliasing on all access patterns.
#define P(x) ((x) + ((x) >> 4))
#define BUF_SZ 2176   // P(2047) = 2174

// K in stage-permuted order: 512 x 2048 complex = 8 MB BSS (graph-safe).
__device__ __align__(16) float2 g_kf[(size_t)NH * FFT_N];

__device__ __forceinline__ float2 cmul(float2 a, float2 b) {
    return make_float2(a.x * b.x - a.y * b.y, a.x * b.y + a.y * b.x);
}
__device__ __forceinline__ float2 cmulj(float2 a, float2 b) {  // a * conj(b)
    return make_float2(a.x * b.x + a.y * b.y, a.y * b.x - a.x * b.y);
}
__device__ __forceinline__ float2 cadd(float2 a, float2 b) { return make_float2(a.x + b.x, a.y + b.y); }
__device__ __forceinline__ float2 csub(float2 a, float2 b) { return make_float2(a.x - b.x, a.y - b.y); }

// In-place DFT4, natural order. SIGN=-1 fwd, SIGN=+1 inverse.
template <int SIGN>
__device__ __forceinline__ void dft4(float2 x[4]) {
    float2 s0 = cadd(x[0], x[2]), s1 = csub(x[0], x[2]);
    float2 s2 = cadd(x[1], x[3]), s3 = csub(x[1], x[3]);
    x[0] = cadd(s0, s2);
    x[2] = csub(s0, s2);
    if (SIGN < 0) {
        x[1] = make_float2(s1.x + s3.y, s1.y - s3.x);  // s1 - i*s3
        x[3] = make_float2(s1.x - s3.y, s1.y + s3.x);  // s1 + i*s3
    } else {
        x[1] = make_float2(s1.x - s3.y, s1.y + s3.x);
        x[3] = make_float2(s1.x + s3.y, s1.y - s3.x);
    }
}

// In-place DFT8, natural order (verified R4-R6).
template <int SIGN>
__device__ __forceinline__ void dft8(float2 x[8]) {
    float2 e0 = cadd(x[0], x[4]), e1 = cadd(x[1], x[5]);
    float2 e2 = cadd(x[2], x[6]), e3 = cadd(x[3], x[7]);
    float2 o0 = csub(x[0], x[4]), o1 = csub(x[1], x[5]);
    float2 o2 = csub(x[2], x[6]), o3 = csub(x[3], x[7]);
    float2 t1, t2, t3;
    if (SIGN < 0) {
        t1 = make_float2(RS * (o1.x + o1.y), RS * (o1.y - o1.x));
        t2 = make_float2(o2.y, -o2.x);
        t3 = make_float2(-RS * (o3.x - o3.y), -RS * (o3.x + o3.y));
    } else {
        t1 = make_float2(RS * (o1.x - o1.y), RS * (o1.x + o1.y));
        t2 = make_float2(-o2.y, o2.x);
        t3 = make_float2(RS * (-o3.x - o3.y), RS * (o3.x - o3.y));
    }
    float2 s0 = cadd(e0, e2), s1 = csub(e0, e2), s2 = cadd(e1, e3), s3 = csub(e1, e3);
    x[0] = cadd(s0, s2);
    x[4] = csub(s0, s2);
    float2 u0 = cadd(o0, t2), u1 = csub(o0, t2), u2 = cadd(t1, t3), u3 = csub(t1, t3);
    x[1] = cadd(u0, u2);
    x[5] = csub(u0, u2);
    if (SIGN < 0) {
        x[2] = make_float2(s1.x + s3.y, s1.y - s3.x);
        x[6] = make_float2(s1.x - s3.y, s1.y + s3.x);
        x[3] = make_float2(u1.x + u3.y, u1.y - u3.x);
        x[7] = make_float2(u1.x - u3.y, u1.y + u3.x);
    } else {
        x[2] = make_float2(s1.x - s3.y, s1.y + s3.x);
        x[6] = make_float2(s1.x + s3.y, s1.y - s3.x);
        x[3] = make_float2(u1.x - u3.y, u1.y + u3.x);
        x[7] = make_float2(u1.x + u3.y, u1.y - u3.x);
    }
}

// Internal W16 twiddles for the 4x4 CT decomposition of DFT16.
template <int SIGN>
__device__ __forceinline__ void dft16_twiddle(float2 v[4][4]) {
    const float sg = (SIGN < 0) ? -1.f : 1.f;
    const float2 W1 = make_float2(C16, sg * S16);
    const float2 W2 = make_float2(RS, sg * RS);
    const float2 W3 = make_float2(S16, sg * C16);
    const float2 W6 = make_float2(-RS, sg * RS);
    const float2 W9 = make_float2(-C16, -sg * S16);
    v[1][1] = cmul(v[1][1], W1);
    v[1][2] = cmul(v[1][2], W2);
    v[1][3] = cmul(v[1][3], W3);
    v[2][1] = cmul(v[2][1], W2);
    v[2][2] = make_float2(-sg * v[2][2].y, sg * v[2][2].x);  // *W16^4
    v[2][3] = cmul(v[2][3], W6);
    v[3][1] = cmul(v[3][1], W3);
    v[3][2] = cmul(v[3][2], W6);
    v[3][3] = cmul(v[3][3], W9);
}

// Full in-place DFT16, natural order.
template <int SIGN>
__device__ __forceinline__ void dft16(float2 x[16]) {
    float2 v[4][4];
#pragma unroll
    for (int n0 = 0; n0 < 4; ++n0) {
        float2 a[4] = {x[n0], x[n0 + 4], x[n0 + 8], x[n0 + 12]};
        dft4<SIGN>(a);
        v[n0][0] = a[0]; v[n0][1] = a[1]; v[n0][2] = a[2]; v[n0][3] = a[3];
    }
    dft16_twiddle<SIGN>(v);
#pragma unroll
    for (int k0 = 0; k0 < 4; ++k0) {
        float2 a[4] = {v[0][k0], v[1][k0], v[2][k0], v[3][k0]};
        dft4<SIGN>(a);
        x[k0] = a[0]; x[k0 + 4] = a[1]; x[k0 + 8] = a[2]; x[k0 + 12] = a[3];
    }
}

// Forward DFT16 with inputs 8..15 implicitly zero.
__device__ __forceinline__ void dft16_zero8(const float2 z[8], float2 x[16]) {
    float2 v[4][4];
#pragma unroll
    for (int n0 = 0; n0 < 4; ++n0) {
        float2 a = z[n0], b = z[n0 + 4];
        v[n0][0] = cadd(a, b);
        v[n0][1] = make_float2(a.x + b.y, a.y - b.x);   // a - i*b
        v[n0][2] = csub(a, b);
        v[n0][3] = make_float2(a.x - b.y, a.y + b.x);   // a + i*b
    }
    dft16_twiddle<-1>(v);
#pragma unroll
    for (int k0 = 0; k0 < 4; ++k0) {
        float2 a[4] = {v[0][k0], v[1][k0], v[2][k0], v[3][k0]};
        dft4<-1>(a);
        x[k0] = a[0]; x[k0 + 4] = a[1]; x[k0 + 8] = a[2]; x[k0 + 12] = a[3];
    }
}

// Inverse DFT16 computing only outputs 0..7.
__device__ __forceinline__ void dft16_inv_low8(const float2 x[16], float2 y[8]) {
    float2 v[4][4];
#pragma unroll
    for (int n0 = 0; n0 < 4; ++n0) {
        float2 a[4] = {x[n0], x[n0 + 4], x[n0 + 8], x[n0 + 12]};
        dft4<+1>(a);
        v[n0][0] = a[0]; v[n0][1] = a[1]; v[n0][2] = a[2]; v[n0][3] = a[3];
    }
    dft16_twiddle<+1>(v);
#pragma unroll
    for (int k0 = 0; k0 < 4; ++k0) {
        float2 x0 = v[0][k0], x1 = v[1][k0], x2 = v[2][k0], x3 = v[3][k0];
        float2 s0 = cadd(x0, x2), s1 = csub(x0, x2);
        float2 s2 = cadd(x1, x3), s3 = csub(x1, x3);
        y[k0]     = cadd(s0, s2);                             // k1 = 0
        y[k0 + 4] = make_float2(s1.x - s3.y, s1.y + s3.x);    // k1 = 1
    }
}

// Apply x[c] *= a^c (CONJ=0) or x[c] *= conj(a^c) (CONJ=1), c = 1..15.
// Log-depth power tree (depth <=5 vs 15 for a serial chain).
template <int CONJ>
__device__ __forceinline__ void tw_apply16(float2 x[16], float2 a) {
#define AP(v, w) (v) = CONJ ? cmulj((v), (w)) : cmul((v), (w))
    AP(x[1], a);
    float2 w2 = cmul(a, a);      AP(x[2], w2);
    float2 w3 = cmul(w2, a);     AP(x[3], w3);
    float2 w4 = cmul(w2, w2);    AP(x[4], w4);
    float2 w5 = cmul(w4, a);     AP(x[5], w5);
    float2 w6 = cmul(w4, w2);    AP(x[6], w6);
    float2 w7 = cmul(w6, a);     AP(x[7], w7);
    float2 w8 = cmul(w4, w4);    AP(x[8], w8);
    float2 w9 = cmul(w8, a);     AP(x[9], w9);
    float2 w10 = cmul(w8, w2);   AP(x[10], w10);
    float2 w11 = cmul(w10, a);   AP(x[11], w11);
    float2 w12 = cmul(w8, w4);   AP(x[12], w12);
    float2 w13 = cmul(w12, a);   AP(x[13], w13);
    float2 w14 = cmul(w12, w2);  AP(x[14], w14);
    float2 w15 = cmul(w14, a);   AP(x[15], w15);
#undef AP
}

// ---- Kernel 1: K = fwd-chain(pad(k[h])) stored in stage-permuted order ----
__global__ __launch_bounds__(NT, 2) void kfft_kernel(const float* __restrict__ kin) {
    __shared__ float re[BUF_SZ];
    __shared__ float im[BUF_SZ];
    __shared__ float2 twlds[NT];
    const int t = threadIdx.x;
    const int h = blockIdx.x;
    float2 w1;
    {
        float sv, cv;
        sincosf(-6.283185307179586f * (float)t / (float)FFT_N, &sv, &cv);
        w1 = make_float2(cv, sv);
        twlds[t] = w1;
    }
    const float* krow = kin + (size_t)h * SEQ_L;
    {
        float2 z[8], x[16];
#pragma unroll
        for (int j = 0; j < 8; ++j) z[j] = make_float2(krow[t + 128 * j], 0.f);
        dft16_zero8(z, x);
        tw_apply16<0>(x, w1);
#pragma unroll
        for (int c = 0; c < 16; ++c) {
            const int id = P(t + 128 * c);
            re[id] = x[c].x; im[id] = x[c].y;
        }
    }
    __syncthreads();
    const int cblk = t >> 3, r = t & 7;
    const int base = 128 * cblk + r;
    {
        float2 x[16];
#pragma unroll
        for (int j = 0; j < 16; ++j) {
            const int id = P(base + 8 * j);
            x[j] = make_float2(re[id], im[id]);
        }
        dft16<-1>(x);
        tw_apply16<0>(x, twlds[16 * r]);
#pragma unroll
        for (int c2 = 0; c2 < 16; ++c2) {
            const int id = P(base + 8 * c2);
            re[id] = x[c2].x; im[id] = x[c2].y;
        }
    }
    __syncthreads();
#pragma unroll
    for (int gi = 0; gi < 2; ++gi) {
        const int g = 2 * t + gi;
        float2 x[8];
#pragma unroll
        for (int l = 0; l < 8; ++l) {
            const int id = P(8 * g + l);
            x[l] = make_float2(re[id], im[id]);
        }
        dft8<-1>(x);
        float4* o4 = (float4*)(g_kf + (size_t)h * FFT_N + 8 * g);
#pragma unroll
        for (int l = 0; l < 4; ++l)
            o4[l] = make_float4(x[2 * l].x, x[2 * l].y, x[2 * l + 1].x, x[2 * l + 1].y);
    }
}

// ---- Kernel 2: rows (2bp,h),(2bp+1,h) packed: fwd chain -> *K -> adjoint ----
__global__ __launch_bounds__(NT, 2) void conv_pair_kernel(const float* __restrict__ u,
                                                          const float* __restrict__ D,
                                                          float* __restrict__ out) {
    __shared__ float re[BUF_SZ];
    __shared__ float im[BUF_SZ];
    __shared__ float2 twlds[NT];
    const int t = threadIdx.x;
    const int h = blockIdx.x & (NH - 1);
    const int bp = blockIdx.x >> 9;
    const size_t row0 = (size_t)(2 * bp) * NH + h;
    const size_t row1 = row0 + NH;
    float2 w1;
    {
        float sv, cv;
        sincosf(-6.283185307179586f * (float)t / (float)FFT_N, &sv, &cv);
        w1 = make_float2(cv, sv);
        twlds[t] = w1;
    }
    const float* u0 = u + row0 * SEQ_L;
    const float* u1 = u + row1 * SEQ_L;
    // s1 fwd (write-only into LDS); u loaded fresh, NOT kept live
    {
        float2 z[8], x[16];
#pragma unroll
        for (int j = 0; j < 8; ++j)
            z[j] = make_float2(u0[t + 128 * j], u1[t + 128 * j]);
        dft16_zero8(z, x);
        tw_apply16<0>(x, w1);
#pragma unroll
        for (int c = 0; c < 16; ++c) {
            const int id = P(t + 128 * c);
            re[id] = x[c].x; im[id] = x[c].y;
        }
    }
    __syncthreads();
    // s2 fwd (in-place)
    const int cblk = t >> 3, r = t & 7;
    const int base = 128 * cblk + r;
    const float2 ws = twlds[16 * r];   // W_128^r
    {
        float2 x[16];
#pragma unroll
        for (int j = 0; j < 16; ++j) {
            const int id = P(base + 8 * j);
            x[j] = make_float2(re[id], im[id]);
        }
        dft16<-1>(x);
        tw_apply16<0>(x, ws);
#pragma unroll
        for (int c2 = 0; c2 < 16; ++c2) {
            const int id = P(base + 8 * c2);
            re[id] = x[c2].x; im[id] = x[c2].y;
        }
    }
    __syncthreads();
    // mid: dft8 fwd + elementwise *K + dft8 inv, all in registers
    {
        const float2* kfr = g_kf + (size_t)h * FFT_N;
#pragma unroll
        for (int gi = 0; gi < 2; ++gi) {
            const int g = 2 * t + gi;
            float2 x[8];
#pragma unroll
            for (int l = 0; l < 8; ++l) {
                const int id = P(8 * g + l);
                x[l] = make_float2(re[id], im[id]);
            }
            dft8<-1>(x);
            const float4* k4 = (const float4*)(kfr + 8 * g);
#pragma unroll
            for (int l = 0; l < 4; ++l) {
                float4 kk = k4[l];
                x[2 * l]     = cmul(x[2 * l],     make_float2(kk.x, kk.y));
                x[2 * l + 1] = cmul(x[2 * l + 1], make_float2(kk.z, kk.w));
            }
            dft8<+1>(x);
#pragma unroll
            for (int l = 0; l < 8; ++l) {
                const int id = P(8 * g + l);
                re[id] = x[l].x; im[id] = x[l].y;
            }
        }
    }
    __syncthreads();
    // prefetch epilogue u values (L1/L2-hot) so they're in flight over inv s2
    float up0[8], up1[8];
#pragma unroll
    for (int j = 0; j < 8; ++j) {
        up0[j] = u0[t + 128 * j];
        up1[j] = u1[t + 128 * j];
    }
    // inv s2 (adjoint: conj twiddle, then inverse butterfly; in-place)
    {
        float2 x[16];
#pragma unroll
        for (int c2 = 0; c2 < 16; ++c2) {
            const int id = P(base + 8 * c2);
            x[c2] = make_float2(re[id], im[id]);
        }
        tw_apply16<1>(x, ws);
        dft16<+1>(x);
#pragma unroll
        for (int j = 0; j < 16; ++j) {
            const int id = P(base + 8 * j);
            re[id] = x[j].x; im[id] = x[j].y;
        }
    }
    __syncthreads();
    // inv s1 + epilogue (only low 8 outputs needed)
    {
        float2 x[16];
#pragma unroll
        for (int c = 0; c < 16; ++c) {
            const int id = P(t + 128 * c);
            x[c] = make_float2(re[id], im[id]);
        }
        tw_apply16<1>(x, w1);
        float2 y[8];
        dft16_inv_low8(x, y);
        const float Dh = D[h];
        const float invN = 1.0f / (float)FFT_N;
        float* o0row = out + row0 * SEQ_L;
        float* o1row = out + row1 * SEQ_L;
#pragma unroll
        for (int j = 0; j < 8; ++j) {
            o0row[t + 128 * j] = y[j].x * invN + up0[j] * Dh;
            o1row[t + 128 * j] = y[j].y * invN + up1[j] * Dh;
        }
    }
}

extern "C" void kernel_launch(void* const* d_in, const int* in_sizes, int n_in,
                              void* d_out, int out_size, void* d_ws, size_t ws_size,
                              hipStream_t stream) {
    const float* u = (const float*)d_in[0];
    const float* k = (const float*)d_in[1];
    const float* D = (const float*)d_in[2];
    float* out = (float*)d_out;

    kfft_kernel<<<NH, NT, 0, stream>>>(k);
    conv_pair_kernel<<<NB * NH / 2, NT, 0, stream>>>(u, D, out);
}